// Round 8
// baseline (1155.616 us; speedup 1.0000x reference)
//
#include <hip/hip_runtime.h>
#include <hip/hip_bf16.h>

#define N_ 8192
#define I_ 1024
#define O_ 1024
#define P_ 8
#define C_ 64
#define OP_ (O_ * P_)

typedef float f32x4 __attribute__((ext_vector_type(4)));
typedef __bf16 bf16x8 __attribute__((ext_vector_type(8)));
typedef unsigned short ushort8 __attribute__((ext_vector_type(8)));

#define GLOBAL_AS(p) ((const __attribute__((address_space(1))) unsigned int*)(p))
#define LDS_AS(p) ((__attribute__((address_space(3))) unsigned int*)(p))

// ---------------------------------------------------------------------------
// Kernel A0: proto_sq[o*8+p] = sum_c protos[o,p,c]^2  (fp32, exact)
// ---------------------------------------------------------------------------
__global__ void psq_kernel(const float* __restrict__ protos, float* __restrict__ psq) {
    const int idx = blockIdx.x * 256 + threadIdx.x;  // 0..8191
    const float* pr = protos + (size_t)idx * C_;
    float s = 0.f;
    #pragma unroll
    for (int c = 0; c < C_; ++c) s = fmaf(pr[c], pr[c], s);
    psq[idx] = s;
}

// ---------------------------------------------------------------------------
// Kernel S: split fp32 -> bf16 hi + lo (x = hi + lo + O(2^-17 x)).
// ---------------------------------------------------------------------------
__global__ __launch_bounds__(256)
void split_bf16_kernel(const float* __restrict__ src, unsigned short* __restrict__ hi,
                       unsigned short* __restrict__ lo) {
    const int idx = blockIdx.x * 256 + threadIdx.x;
    const float* sp = src + (size_t)idx * 8;
    const float4 f0 = *(const float4*)(sp);
    const float4 f1 = *(const float4*)(sp + 4);
    float f[8] = {f0.x, f0.y, f0.z, f0.w, f1.x, f1.y, f1.z, f1.w};
    ushort8 vh, vl;
    #pragma unroll
    for (int e = 0; e < 8; ++e) {
        const __hip_bfloat16 h = __float2bfloat16(f[e]);
        const __hip_bfloat16 l = __float2bfloat16(f[e] - __bfloat162float(h));
        vh[e] = __builtin_bit_cast(unsigned short, h);
        vl[e] = __builtin_bit_cast(unsigned short, l);
    }
    *(ushort8*)(hi + (size_t)idx * 8) = vh;
    *(ushort8*)(lo + (size_t)idx * 8) = vl;
}

// ---------------------------------------------------------------------------
// Kernel A: argmin via split-bf16 MFMA. cross = Ah*Bh + Ah*Bl + Al*Bh.
// Static-index epilogue (no scratch), near-ties flagged in-place via bit 7
// of best (no atomics / worklist). lk-even lanes own p=0..3; partner
// (shfl_xor 16) holds p=4..7 of the same o.
// ---------------------------------------------------------------------------
__global__ __launch_bounds__(256, 2)
void argmin_mfma_kernel(const unsigned short* __restrict__ ph, const unsigned short* __restrict__ pl,
                        const unsigned short* __restrict__ ch, const unsigned short* __restrict__ cl,
                        const float* __restrict__ psq, unsigned char* __restrict__ best) {
    const int tid = threadIdx.x;
    const int w = tid >> 6, l = tid & 63;
    const int op0 = blockIdx.x * 128;
    const int nw = blockIdx.y * 128 + w * 32;
    const int lr = l & 15, lk = l >> 4;

    f32x4 acc[8][2];
    #pragma unroll
    for (int of = 0; of < 8; ++of)
        #pragma unroll
        for (int nf = 0; nf < 2; ++nf) acc[of][nf] = (f32x4)(0.f);

    #pragma unroll
    for (int ks = 0; ks < 2; ++ks) {
        const int ko = ks * 32 + lk * 8;
        bf16x8 Ah[8], Al[8], Bh[2], Bl[2];
        #pragma unroll
        for (int of = 0; of < 8; ++of) {
            const size_t r = (size_t)(op0 + of * 16 + lr) * C_ + ko;
            Ah[of] = *(const bf16x8*)(ph + r);
            Al[of] = *(const bf16x8*)(pl + r);
        }
        #pragma unroll
        for (int nf = 0; nf < 2; ++nf) {
            const size_t r = (size_t)(nw + nf * 16 + lr) * C_ + ko;
            Bh[nf] = *(const bf16x8*)(ch + r);
            Bl[nf] = *(const bf16x8*)(cl + r);
        }
        #pragma unroll
        for (int of = 0; of < 8; ++of)
            #pragma unroll
            for (int nf = 0; nf < 2; ++nf) {
                acc[of][nf] = __builtin_amdgcn_mfma_f32_16x16x32_bf16(Ah[of], Bh[nf], acc[of][nf], 0, 0, 0);
                acc[of][nf] = __builtin_amdgcn_mfma_f32_16x16x32_bf16(Ah[of], Bl[nf], acc[of][nf], 0, 0, 0);
                acc[of][nf] = __builtin_amdgcn_mfma_f32_16x16x32_bf16(Al[of], Bh[nf], acc[of][nf], 0, 0, 0);
            }
    }

    #pragma unroll
    for (int of = 0; of < 8; ++of) {
        const int oprow0 = op0 + of * 16;
        const f32x4 ps = *(const f32x4*)(psq + oprow0 + lk * 4);
        #pragma unroll
        for (int nf = 0; nf < 2; ++nf) {
            const float d0 = fmaf(-2.f, acc[of][nf][0], ps[0]);
            const float d1 = fmaf(-2.f, acc[of][nf][1], ps[1]);
            const float d2 = fmaf(-2.f, acc[of][nf][2], ps[2]);
            const float d3 = fmaf(-2.f, acc[of][nf][3], ps[3]);
            const float e0 = __shfl_xor(d0, 16, 64);
            const float e1 = __shfl_xor(d1, 16, 64);
            const float e2 = __shfl_xor(d2, 16, 64);
            const float e3 = __shfl_xor(d3, 16, 64);
            float b1v = 3.4e38f, b2v = 3.4e38f;
            int bi = 0;
            #define UPD(val, pidx) do { const float _f = (val);                       \
                if (_f < b1v) { b2v = b1v; b1v = _f; bi = (pidx); }                   \
                else if (_f < b2v) b2v = _f; } while (0)
            UPD(d0, 0); UPD(d1, 1); UPD(d2, 2); UPD(d3, 3);
            UPD(e0, 4); UPD(e1, 5); UPD(e2, 6); UPD(e3, 7);
            #undef UPD
            if ((lk & 1) == 0) {
                const int o = (oprow0 >> 3) + (lk >> 1);
                const int n = nw + nf * 16 + lr;
                const unsigned flag = (b2v - b1v < 0.03f) ? 0x80u : 0u;
                best[(size_t)o * N_ + n] = (unsigned char)((unsigned)bi | flag);
            }
        }
    }
}

// ---------------------------------------------------------------------------
// Kernel A2: bitmap-scan exact fp64 refine. Scans best for bit-7 flags set
// by argmin; recomputes exact argmin for those (n,o); clears the flag.
// 16 bytes per thread, grid covers all O*N bytes.
// ---------------------------------------------------------------------------
__global__ __launch_bounds__(256)
void refine_kernel(const float* __restrict__ ctx, const float* __restrict__ protos,
                   unsigned char* __restrict__ best) {
    const int idx = blockIdx.x * 256 + threadIdx.x;  // 524288 threads
    const size_t base = (size_t)idx * 16;
    const uint4 v = *(const uint4*)(best + base);
    if (((v.x | v.y | v.z | v.w) & 0x80808080u) == 0) return;
    const unsigned words[4] = {v.x, v.y, v.z, v.w};
    #pragma unroll
    for (int wq = 0; wq < 4; ++wq) {
        const unsigned wv = words[wq];
        if ((wv & 0x80808080u) == 0) continue;
        #pragma unroll
        for (int bq = 0; bq < 4; ++bq) {
            if ((wv >> (8 * bq + 7)) & 1u) {
                const size_t off = base + wq * 4 + bq;
                const int n = (int)(off & (N_ - 1));
                const int o = (int)(off >> 13);
                const float* cr = ctx + (size_t)n * C_;
                double dmin = 1e300;
                int bi = 0;
                for (int p = 0; p < 8; ++p) {
                    const float* pr = protos + ((size_t)o * 8 + p) * C_;
                    double s = 0.0;
                    for (int c = 0; c < C_; ++c) {
                        const double pv = (double)pr[c];
                        const double cv = (double)cr[c];
                        s += pv * (pv - 2.0 * cv);
                    }
                    if (s < dmin) { dmin = s; bi = p; }
                }
                best[off] = (unsigned char)bi;
            }
        }
    }
}

// ---------------------------------------------------------------------------
// Kernel C: fp32 -> bf16 into half-tile-blocked, row-XOR-swizzled layout
// (validated round 7).
// ---------------------------------------------------------------------------
template<int LAYOUT>
__global__ __launch_bounds__(256)
void convert_tiled_kernel(const float* __restrict__ src, unsigned short* __restrict__ dst) {
    const int idx = blockIdx.x * 256 + threadIdx.x;  // 1,048,576 chunks
    const int rb = idx >> 15;
    const int r = idx & 32767;
    const int kt = r >> 11;
    const int h = (r >> 10) & 1;
    const int L = r & 1023;
    const int Lr = L >> 3;
    const int j = L & 7;
    const int c = j ^ (Lr & 7);
    int Rlocal;
    if (LAYOUT == 0) Rlocal = (Lr & 63) + ((Lr & 64) << 1) + h * 64;
    else             Rlocal = ((Lr >> 5) << 6) + h * 32 + (Lr & 31);
    const int gR = rb * 256 + Rlocal;
    const int k0 = kt * 64 + c * 8;
    const float* sp = src + (size_t)gR * I_ + k0;
    const float4 f0 = *(const float4*)(sp);
    const float4 f1 = *(const float4*)(sp + 4);
    ushort8 v;
    v[0] = __builtin_bit_cast(unsigned short, __float2bfloat16(f0.x));
    v[1] = __builtin_bit_cast(unsigned short, __float2bfloat16(f0.y));
    v[2] = __builtin_bit_cast(unsigned short, __float2bfloat16(f0.z));
    v[3] = __builtin_bit_cast(unsigned short, __float2bfloat16(f0.w));
    v[4] = __builtin_bit_cast(unsigned short, __float2bfloat16(f1.x));
    v[5] = __builtin_bit_cast(unsigned short, __float2bfloat16(f1.y));
    v[6] = __builtin_bit_cast(unsigned short, __float2bfloat16(f1.z));
    v[7] = __builtin_bit_cast(unsigned short, __float2bfloat16(f1.w));
    *(ushort8*)(dst + (size_t)idx * 8) = v;
}

// ---------------------------------------------------------------------------
// Kernel B: 256x256 phase-pipelined bf16 MFMA GEMM (validated round 7) +
// fused argmin-gather epilogue.
// ---------------------------------------------------------------------------
__global__ __launch_bounds__(512, 1)
void gemm_gather_kernel(const unsigned short* __restrict__ Xb,
                        const unsigned short* __restrict__ Wb,
                        const float* __restrict__ bias,
                        const unsigned char* __restrict__ best,
                        float* __restrict__ out) {
    extern __shared__ unsigned short lds[];  // 2 x (A 16384 + B 16384) ushort = 128 KiB

    int wg = blockIdx.x;                     // 1024 blocks, %8==0 -> bijective
    wg = (wg & 7) * 128 + (wg >> 3);
    const int bx = wg & 31;
    const int by = wg >> 5;
    const int n0 = by * 256;
    const int col0 = bx * 256;

    const int tid = threadIdx.x;
    const int w = tid >> 6, l = tid & 63;
    const int wr = w >> 2, wc = w & 3;
    const int lr = l & 15, lk = l >> 4;
    const int lx = lr & 7;

    const unsigned short* Xrb = Xb + (size_t)(n0 >> 8) * 262144;
    const unsigned short* Wrb = Wb + (size_t)(col0 >> 8) * 262144;

    #define STAGE(src, ktt, h, ldsofs) do {                                          \
        const unsigned short* _g = (src) + ((size_t)(ktt) * 2 + (h)) * 8192;         \
        __builtin_amdgcn_global_load_lds(GLOBAL_AS(_g + (size_t)tid * 8),            \
            LDS_AS(lds + (ldsofs) + tid * 8), 16, 0, 0);                             \
        __builtin_amdgcn_global_load_lds(GLOBAL_AS(_g + (size_t)(tid + 512) * 8),    \
            LDS_AS(lds + (ldsofs) + (tid + 512) * 8), 16, 0, 0);                     \
    } while (0)

    #define VMCNT4() do { asm volatile("s_waitcnt vmcnt(4)" ::: "memory");           \
        __builtin_amdgcn_sched_barrier(0); } while (0)
    #define VMCNT2() do { asm volatile("s_waitcnt vmcnt(2)" ::: "memory");           \
        __builtin_amdgcn_sched_barrier(0); } while (0)
    #define VMCNT0() do { asm volatile("s_waitcnt vmcnt(0)" ::: "memory");           \
        __builtin_amdgcn_sched_barrier(0); } while (0)
    #define LGKM0() do { asm volatile("s_waitcnt lgkmcnt(0)" ::: "memory");          \
        __builtin_amdgcn_sched_barrier(0); } while (0)

    f32x4 acc[8][4];
    #pragma unroll
    for (int m = 0; m < 8; ++m)
        #pragma unroll
        for (int n = 0; n < 4; ++n) acc[m][n] = (f32x4)(0.f);

    #define RD_A(dst, mbase, bb) do {                                                \
        _Pragma("unroll")                                                            \
        for (int _m = 0; _m < 4; ++_m) {                                             \
            const int _R = wr * 128 + ((mbase) + _m) * 16 + lr;                      \
            const int _h = (_R >> 6) & 1;                                            \
            const int _Lr = (_R & 63) + ((_R & 128) >> 1);                           \
            _Pragma("unroll")                                                        \
            for (int _k = 0; _k < 2; ++_k) {                                         \
                const int _s = (_k * 4 + lk) ^ lx;                                   \
                dst[_m][_k] = *(const bf16x8*)&lds[(bb) * 32768 + _h * 8192 +        \
                                                   _Lr * 64 + _s * 8];               \
            }                                                                        \
        }                                                                            \
    } while (0)

    #define RD_B(dst, nbase, bb) do {                                                \
        _Pragma("unroll")                                                            \
        for (int _n = 0; _n < 2; ++_n) {                                             \
            const int _R = wc * 64 + ((nbase) + _n) * 16 + lr;                       \
            const int _h = (_R >> 5) & 1;                                            \
            const int _Lr = ((_R >> 6) << 5) + (_R & 31);                            \
            _Pragma("unroll")                                                        \
            for (int _k = 0; _k < 2; ++_k) {                                         \
                const int _s = (_k * 4 + lk) ^ lx;                                   \
                dst[_n][_k] = *(const bf16x8*)&lds[(bb) * 32768 + 16384 +            \
                                                   _h * 8192 + _Lr * 64 + _s * 8];   \
            }                                                                        \
        }                                                                            \
    } while (0)

    #define MFMA16(AF, BF, MB, NB) do {                                              \
        __builtin_amdgcn_s_setprio(1);                                               \
        _Pragma("unroll")                                                            \
        for (int _m = 0; _m < 4; ++_m)                                               \
            _Pragma("unroll")                                                        \
            for (int _n = 0; _n < 2; ++_n)                                           \
                _Pragma("unroll")                                                    \
                for (int _k = 0; _k < 2; ++_k)                                       \
                    acc[(MB) + _m][(NB) + _n] =                                      \
                        __builtin_amdgcn_mfma_f32_16x16x32_bf16(                     \
                            AF[_m][_k], BF[_n][_k], acc[(MB) + _m][(NB) + _n], 0, 0, 0); \
        __builtin_amdgcn_s_setprio(0);                                               \
    } while (0)

    bf16x8 af[4][2], bfa[2][2], bfb[2][2];

    // ---- prologue: stage kt0 {Aa,Ba,Bb,Ab}; drain Aa0,Ba0 ----
    STAGE(Xrb, 0, 0, 0);              // A-alpha(0)
    STAGE(Wrb, 0, 0, 16384);          // B-alpha(0)
    STAGE(Wrb, 0, 1, 16384 + 8192);   // B-beta(0)
    STAGE(Xrb, 0, 1, 8192);           // A-beta(0)
    VMCNT4();
    __builtin_amdgcn_s_barrier();

    #pragma unroll 1
    for (int kt = 0; kt < 15; ++kt) {
        const int b = kt & 1, nb = b ^ 1;
        const int nbo = nb * 32768;
        // P1: read Aa(m0-3)+Ba(n0-1); stage Ba(kt+1)
        RD_A(af, 0, b);
        RD_B(bfa, 0, b);
        STAGE(Wrb, kt + 1, 0, nbo + 16384);
        VMCNT4();
        __builtin_amdgcn_s_barrier();
        LGKM0();
        MFMA16(af, bfa, 0, 0);
        // P2: read Bb(n2-3); stage Aa(kt+1)
        RD_B(bfb, 2, b);
        STAGE(Xrb, kt + 1, 0, nbo);
        VMCNT4();
        __builtin_amdgcn_s_barrier();
        LGKM0();
        MFMA16(af, bfb, 0, 2);
        // P3: read Ab(m4-7); stage Bb(kt+1)
        RD_A(af, 4, b);
        STAGE(Wrb, kt + 1, 1, nbo + 16384 + 8192);
        VMCNT4();
        __builtin_amdgcn_s_barrier();
        LGKM0();
        MFMA16(af, bfb, 4, 2);
        // P4: re-read Ba(n0-1); stage Ab(kt+1)
        RD_B(bfa, 0, b);
        STAGE(Xrb, kt + 1, 1, nbo + 8192);
        VMCNT4();
        __builtin_amdgcn_s_barrier();
        LGKM0();
        MFMA16(af, bfa, 4, 0);
    }
    // ---- tail kt=15 (buf 1, no staging) ----
    {
        RD_A(af, 0, 1);
        RD_B(bfa, 0, 1);
        VMCNT2();
        __builtin_amdgcn_s_barrier();
        LGKM0();
        MFMA16(af, bfa, 0, 0);
        RD_B(bfb, 2, 1);
        VMCNT0();
        __builtin_amdgcn_s_barrier();
        LGKM0();
        MFMA16(af, bfb, 0, 2);
        RD_A(af, 4, 1);
        LGKM0();
        MFMA16(af, bfb, 4, 2);
        RD_B(bfa, 0, 1);
        LGKM0();
        MFMA16(af, bfa, 4, 0);
    }

    // ---- epilogue: fused argmin-gather + bias; u32 best loads ----
    const int nbase = n0 + wr * 128 + lk * 4;
    #pragma unroll
    for (int nf = 0; nf < 4; ++nf) {
        const int opcol = col0 + wc * 64 + nf * 16 + lr;
        const int o = opcol >> 3;
        const unsigned p = (unsigned)(opcol & 7);
        const float bv = bias[opcol];
        const unsigned char* brow = best + (size_t)o * N_ + nbase;
        #pragma unroll
        for (int m = 0; m < 8; ++m) {
            const unsigned b4 = *(const unsigned*)(brow + m * 16);
            #pragma unroll
            for (int j = 0; j < 4; ++j) {
                if (((b4 >> (j * 8)) & 255u) == p) {
                    const int n = nbase + m * 16 + j;
                    out[(size_t)n * O_ + o] = acc[m][nf][j] + bv;
                }
            }
        }
    }
    #undef STAGE
    #undef RD_A
    #undef RD_B
    #undef MFMA16
    #undef VMCNT4
    #undef VMCNT2
    #undef VMCNT0
    #undef LGKM0
}

// ---------------------------------------------------------------------------
extern "C" void kernel_launch(void* const* d_in, const int* in_sizes, int n_in,
                              void* d_out, int out_size, void* d_ws, size_t ws_size,
                              hipStream_t stream) {
    const float* X      = (const float*)d_in[0];
    const float* ctx    = (const float*)d_in[1];
    const float* W      = (const float*)d_in[2];
    const float* bias   = (const float*)d_in[3];
    const float* protos = (const float*)d_in[4];
    float* out = (float*)d_out;

    char* ws = (char*)d_ws;
    unsigned char* best = (unsigned char*)ws;                         // 8 MiB
    float* psq = (float*)(ws + ((size_t)8 << 20));                    // 32 KiB
    unsigned short* Xb = (unsigned short*)(ws + ((size_t)9 << 20));   // 16 MiB
    unsigned short* Wb = (unsigned short*)(ws + ((size_t)25 << 20));  // 16 MiB

    // split-bf16 scratch lives in d_out (fully overwritten by gemm later)
    char* ob = (char*)d_out;
    unsigned short* ph = (unsigned short*)(ob + ((size_t)16 << 20));  // 1 MiB
    unsigned short* pl = (unsigned short*)(ob + ((size_t)17 << 20));  // 1 MiB
    unsigned short* ch = (unsigned short*)(ob + ((size_t)18 << 20));  // 1 MiB
    unsigned short* cl = (unsigned short*)(ob + ((size_t)19 << 20));  // 1 MiB

    hipFuncSetAttribute((const void*)gemm_gather_kernel,
                        hipFuncAttributeMaxDynamicSharedMemorySize, 131072);

    convert_tiled_kernel<0><<<dim3(4096), dim3(256), 0, stream>>>(X, Xb);
    convert_tiled_kernel<1><<<dim3(4096), dim3(256), 0, stream>>>(W, Wb);
    psq_kernel<<<dim3(32), dim3(256), 0, stream>>>(protos, psq);
    split_bf16_kernel<<<dim3(256), dim3(256), 0, stream>>>(protos, ph, pl);
    split_bf16_kernel<<<dim3(256), dim3(256), 0, stream>>>(ctx, ch, cl);
    argmin_mfma_kernel<<<dim3(OP_ / 128, N_ / 128), dim3(256), 0, stream>>>(ph, pl, ch, cl, psq, best);
    refine_kernel<<<dim3(2048), dim3(256), 0, stream>>>(ctx, protos, best);
    gemm_gather_kernel<<<dim3(1024), dim3(512), 131072, stream>>>(Xb, Wb, bias, best, out);
}

// Round 9
// 645.084 us; speedup vs baseline: 1.7914x; 1.7914x over previous
//
#include <hip/hip_runtime.h>
#include <hip/hip_bf16.h>

#define N_ 8192
#define I_ 1024
#define O_ 1024
#define P_ 8
#define C_ 64
#define OP_ (O_ * P_)

typedef float f32x4 __attribute__((ext_vector_type(4)));
typedef __bf16 bf16x8 __attribute__((ext_vector_type(8)));
typedef unsigned short ushort8 __attribute__((ext_vector_type(8)));

#define GLOBAL_AS(p) ((const __attribute__((address_space(1))) unsigned int*)(p))
#define LDS_AS(p) ((__attribute__((address_space(3))) unsigned int*)(p))

// ---------------------------------------------------------------------------
// Kernel A0: proto_sq[o*8+p] = sum_c protos[o,p,c]^2  (fp32, exact)
// ---------------------------------------------------------------------------
__global__ void psq_kernel(const float* __restrict__ protos, float* __restrict__ psq) {
    const int idx = blockIdx.x * 256 + threadIdx.x;  // 0..8191
    const float* pr = protos + (size_t)idx * C_;
    float s = 0.f;
    #pragma unroll
    for (int c = 0; c < C_; ++c) s = fmaf(pr[c], pr[c], s);
    psq[idx] = s;
}

// ---------------------------------------------------------------------------
// Kernel S: split fp32 -> bf16 hi + lo (x = hi + lo + O(2^-17 x)).
// ---------------------------------------------------------------------------
__global__ __launch_bounds__(256)
void split_bf16_kernel(const float* __restrict__ src, unsigned short* __restrict__ hi,
                       unsigned short* __restrict__ lo) {
    const int idx = blockIdx.x * 256 + threadIdx.x;
    const float* sp = src + (size_t)idx * 8;
    const float4 f0 = *(const float4*)(sp);
    const float4 f1 = *(const float4*)(sp + 4);
    float f[8] = {f0.x, f0.y, f0.z, f0.w, f1.x, f1.y, f1.z, f1.w};
    ushort8 vh, vl;
    #pragma unroll
    for (int e = 0; e < 8; ++e) {
        const __hip_bfloat16 h = __float2bfloat16(f[e]);
        const __hip_bfloat16 l = __float2bfloat16(f[e] - __bfloat162float(h));
        vh[e] = __builtin_bit_cast(unsigned short, h);
        vl[e] = __builtin_bit_cast(unsigned short, l);
    }
    *(ushort8*)(hi + (size_t)idx * 8) = vh;
    *(ushort8*)(lo + (size_t)idx * 8) = vl;
}

// ---------------------------------------------------------------------------
// Kernel A: argmin via split-bf16 MFMA (validated round 8). Near-ties
// flagged in-place via bit 7 of best; static-index epilogue.
// ---------------------------------------------------------------------------
__global__ __launch_bounds__(256, 2)
void argmin_mfma_kernel(const unsigned short* __restrict__ ph, const unsigned short* __restrict__ pl,
                        const unsigned short* __restrict__ ch, const unsigned short* __restrict__ cl,
                        const float* __restrict__ psq, unsigned char* __restrict__ best) {
    const int tid = threadIdx.x;
    const int w = tid >> 6, l = tid & 63;
    const int op0 = blockIdx.x * 128;
    const int nw = blockIdx.y * 128 + w * 32;
    const int lr = l & 15, lk = l >> 4;

    f32x4 acc[8][2];
    #pragma unroll
    for (int of = 0; of < 8; ++of)
        #pragma unroll
        for (int nf = 0; nf < 2; ++nf) acc[of][nf] = (f32x4)(0.f);

    #pragma unroll
    for (int ks = 0; ks < 2; ++ks) {
        const int ko = ks * 32 + lk * 8;
        bf16x8 Ah[8], Al[8], Bh[2], Bl[2];
        #pragma unroll
        for (int of = 0; of < 8; ++of) {
            const size_t r = (size_t)(op0 + of * 16 + lr) * C_ + ko;
            Ah[of] = *(const bf16x8*)(ph + r);
            Al[of] = *(const bf16x8*)(pl + r);
        }
        #pragma unroll
        for (int nf = 0; nf < 2; ++nf) {
            const size_t r = (size_t)(nw + nf * 16 + lr) * C_ + ko;
            Bh[nf] = *(const bf16x8*)(ch + r);
            Bl[nf] = *(const bf16x8*)(cl + r);
        }
        #pragma unroll
        for (int of = 0; of < 8; ++of)
            #pragma unroll
            for (int nf = 0; nf < 2; ++nf) {
                acc[of][nf] = __builtin_amdgcn_mfma_f32_16x16x32_bf16(Ah[of], Bh[nf], acc[of][nf], 0, 0, 0);
                acc[of][nf] = __builtin_amdgcn_mfma_f32_16x16x32_bf16(Ah[of], Bl[nf], acc[of][nf], 0, 0, 0);
                acc[of][nf] = __builtin_amdgcn_mfma_f32_16x16x32_bf16(Al[of], Bh[nf], acc[of][nf], 0, 0, 0);
            }
    }

    #pragma unroll
    for (int of = 0; of < 8; ++of) {
        const int oprow0 = op0 + of * 16;
        const f32x4 ps = *(const f32x4*)(psq + oprow0 + lk * 4);
        #pragma unroll
        for (int nf = 0; nf < 2; ++nf) {
            const float d0 = fmaf(-2.f, acc[of][nf][0], ps[0]);
            const float d1 = fmaf(-2.f, acc[of][nf][1], ps[1]);
            const float d2 = fmaf(-2.f, acc[of][nf][2], ps[2]);
            const float d3 = fmaf(-2.f, acc[of][nf][3], ps[3]);
            const float e0 = __shfl_xor(d0, 16, 64);
            const float e1 = __shfl_xor(d1, 16, 64);
            const float e2 = __shfl_xor(d2, 16, 64);
            const float e3 = __shfl_xor(d3, 16, 64);
            float b1v = 3.4e38f, b2v = 3.4e38f;
            int bi = 0;
            #define UPD(val, pidx) do { const float _f = (val);                       \
                if (_f < b1v) { b2v = b1v; b1v = _f; bi = (pidx); }                   \
                else if (_f < b2v) b2v = _f; } while (0)
            UPD(d0, 0); UPD(d1, 1); UPD(d2, 2); UPD(d3, 3);
            UPD(e0, 4); UPD(e1, 5); UPD(e2, 6); UPD(e3, 7);
            #undef UPD
            if ((lk & 1) == 0) {
                const int o = (oprow0 >> 3) + (lk >> 1);
                const int n = nw + nf * 16 + lr;
                const unsigned flag = (b2v - b1v < 0.03f) ? 0x80u : 0u;
                best[(size_t)o * N_ + n] = (unsigned char)((unsigned)bi | flag);
            }
        }
    }
}

// ---------------------------------------------------------------------------
// Kernel A1.5: compact flagged bytes into a worklist. One u32 word/thread;
// wave-aggregated reservation: inclusive shfl_up scan + ONE atomicAdd/wave.
// ---------------------------------------------------------------------------
__global__ __launch_bounds__(256)
void compact_kernel(const unsigned* __restrict__ bw, unsigned* __restrict__ wl,
                    unsigned* __restrict__ wl_cnt) {
    const int idx = blockIdx.x * 256 + threadIdx.x;  // 2M words
    const unsigned wv = bw[idx];
    const unsigned fl = wv & 0x80808080u;
    const unsigned k = (unsigned)__popc(fl);

    // wave inclusive scan of k
    const int lane = threadIdx.x & 63;
    unsigned s = k;
    #pragma unroll
    for (int d = 1; d < 64; d <<= 1) {
        const unsigned t = __shfl_up(s, d, 64);
        if (lane >= d) s += t;
    }
    const unsigned total = __shfl(s, 63, 64);
    unsigned base = 0;
    if (lane == 63 && total) base = atomicAdd(wl_cnt, total);
    base = __shfl(base, 63, 64);
    unsigned my = base + s - k;  // exclusive prefix

    if (fl) {
        #pragma unroll
        for (int bq = 0; bq < 4; ++bq) {
            if ((fl >> (8 * bq + 7)) & 1u) {
                wl[my++] = (unsigned)idx * 4u + bq;
            }
        }
    }
}

// ---------------------------------------------------------------------------
// Kernel A2: parallel exact fp64 refine. 8 lanes per flagged element
// (lane = proto p); 64-FMA fp64 chain; 3-step shfl_xor argmin reduce with
// smallest-index tie-break (== sequential first-min); lane 0 writes.
// ---------------------------------------------------------------------------
__global__ __launch_bounds__(256)
void refine_wl_kernel(const float* __restrict__ ctx, const float* __restrict__ protos,
                      const unsigned* __restrict__ wl, const unsigned* __restrict__ wl_cnt,
                      unsigned char* __restrict__ best) {
    const unsigned cnt = *wl_cnt;
    const int lane8 = threadIdx.x & 7;
    const unsigned gid = (unsigned)(blockIdx.x * 256 + threadIdx.x) >> 3;
    const unsigned stride = (gridDim.x * 256) >> 3;
    for (unsigned i = gid; i < cnt; i += stride) {
        const unsigned off = wl[i];
        const int n = (int)(off & (N_ - 1));
        const int o = (int)(off >> 13);
        const float* cr = ctx + (size_t)n * C_;
        const float* pr = protos + ((size_t)o * 8 + lane8) * C_;
        double s = 0.0;
        #pragma unroll 8
        for (int c = 0; c < C_; ++c) {
            const double pv = (double)pr[c];
            const double cv = (double)cr[c];
            s += pv * (pv - 2.0 * cv);
        }
        int bi = lane8;
        #pragma unroll
        for (int d = 1; d < 8; d <<= 1) {
            const double s2 = __shfl_xor(s, d, 64);
            const int b2 = __shfl_xor(bi, d, 64);
            if (s2 < s || (s2 == s && b2 < bi)) { s = s2; bi = b2; }
        }
        if (lane8 == 0) best[off] = (unsigned char)bi;
    }
}

// ---------------------------------------------------------------------------
// Kernel C: fp32 -> bf16 into half-tile-blocked, row-XOR-swizzled layout
// (validated round 7).
// ---------------------------------------------------------------------------
template<int LAYOUT>
__global__ __launch_bounds__(256)
void convert_tiled_kernel(const float* __restrict__ src, unsigned short* __restrict__ dst) {
    const int idx = blockIdx.x * 256 + threadIdx.x;  // 1,048,576 chunks
    const int rb = idx >> 15;
    const int r = idx & 32767;
    const int kt = r >> 11;
    const int h = (r >> 10) & 1;
    const int L = r & 1023;
    const int Lr = L >> 3;
    const int j = L & 7;
    const int c = j ^ (Lr & 7);
    int Rlocal;
    if (LAYOUT == 0) Rlocal = (Lr & 63) + ((Lr & 64) << 1) + h * 64;
    else             Rlocal = ((Lr >> 5) << 6) + h * 32 + (Lr & 31);
    const int gR = rb * 256 + Rlocal;
    const int k0 = kt * 64 + c * 8;
    const float* sp = src + (size_t)gR * I_ + k0;
    const float4 f0 = *(const float4*)(sp);
    const float4 f1 = *(const float4*)(sp + 4);
    ushort8 v;
    v[0] = __builtin_bit_cast(unsigned short, __float2bfloat16(f0.x));
    v[1] = __builtin_bit_cast(unsigned short, __float2bfloat16(f0.y));
    v[2] = __builtin_bit_cast(unsigned short, __float2bfloat16(f0.z));
    v[3] = __builtin_bit_cast(unsigned short, __float2bfloat16(f0.w));
    v[4] = __builtin_bit_cast(unsigned short, __float2bfloat16(f1.x));
    v[5] = __builtin_bit_cast(unsigned short, __float2bfloat16(f1.y));
    v[6] = __builtin_bit_cast(unsigned short, __float2bfloat16(f1.z));
    v[7] = __builtin_bit_cast(unsigned short, __float2bfloat16(f1.w));
    *(ushort8*)(dst + (size_t)idx * 8) = v;
}

// ---------------------------------------------------------------------------
// Kernel B: 256x256 phase-pipelined bf16 MFMA GEMM (validated round 7) +
// fused argmin-gather epilogue.
// ---------------------------------------------------------------------------
__global__ __launch_bounds__(512, 1)
void gemm_gather_kernel(const unsigned short* __restrict__ Xb,
                        const unsigned short* __restrict__ Wb,
                        const float* __restrict__ bias,
                        const unsigned char* __restrict__ best,
                        float* __restrict__ out) {
    extern __shared__ unsigned short lds[];  // 2 x (A 16384 + B 16384) ushort = 128 KiB

    int wg = blockIdx.x;                     // 1024 blocks, %8==0 -> bijective
    wg = (wg & 7) * 128 + (wg >> 3);
    const int bx = wg & 31;
    const int by = wg >> 5;
    const int n0 = by * 256;
    const int col0 = bx * 256;

    const int tid = threadIdx.x;
    const int w = tid >> 6, l = tid & 63;
    const int wr = w >> 2, wc = w & 3;
    const int lr = l & 15, lk = l >> 4;
    const int lx = lr & 7;

    const unsigned short* Xrb = Xb + (size_t)(n0 >> 8) * 262144;
    const unsigned short* Wrb = Wb + (size_t)(col0 >> 8) * 262144;

    #define STAGE(src, ktt, h, ldsofs) do {                                          \
        const unsigned short* _g = (src) + ((size_t)(ktt) * 2 + (h)) * 8192;         \
        __builtin_amdgcn_global_load_lds(GLOBAL_AS(_g + (size_t)tid * 8),            \
            LDS_AS(lds + (ldsofs) + tid * 8), 16, 0, 0);                             \
        __builtin_amdgcn_global_load_lds(GLOBAL_AS(_g + (size_t)(tid + 512) * 8),    \
            LDS_AS(lds + (ldsofs) + (tid + 512) * 8), 16, 0, 0);                     \
    } while (0)

    #define VMCNT4() do { asm volatile("s_waitcnt vmcnt(4)" ::: "memory");           \
        __builtin_amdgcn_sched_barrier(0); } while (0)
    #define VMCNT2() do { asm volatile("s_waitcnt vmcnt(2)" ::: "memory");           \
        __builtin_amdgcn_sched_barrier(0); } while (0)
    #define VMCNT0() do { asm volatile("s_waitcnt vmcnt(0)" ::: "memory");           \
        __builtin_amdgcn_sched_barrier(0); } while (0)
    #define LGKM0() do { asm volatile("s_waitcnt lgkmcnt(0)" ::: "memory");          \
        __builtin_amdgcn_sched_barrier(0); } while (0)

    f32x4 acc[8][4];
    #pragma unroll
    for (int m = 0; m < 8; ++m)
        #pragma unroll
        for (int n = 0; n < 4; ++n) acc[m][n] = (f32x4)(0.f);

    #define RD_A(dst, mbase, bb) do {                                                \
        _Pragma("unroll")                                                            \
        for (int _m = 0; _m < 4; ++_m) {                                             \
            const int _R = wr * 128 + ((mbase) + _m) * 16 + lr;                      \
            const int _h = (_R >> 6) & 1;                                            \
            const int _Lr = (_R & 63) + ((_R & 128) >> 1);                           \
            _Pragma("unroll")                                                        \
            for (int _k = 0; _k < 2; ++_k) {                                         \
                const int _s = (_k * 4 + lk) ^ lx;                                   \
                dst[_m][_k] = *(const bf16x8*)&lds[(bb) * 32768 + _h * 8192 +        \
                                                   _Lr * 64 + _s * 8];               \
            }                                                                        \
        }                                                                            \
    } while (0)

    #define RD_B(dst, nbase, bb) do {                                                \
        _Pragma("unroll")                                                            \
        for (int _n = 0; _n < 2; ++_n) {                                             \
            const int _R = wc * 64 + ((nbase) + _n) * 16 + lr;                       \
            const int _h = (_R >> 5) & 1;                                            \
            const int _Lr = ((_R >> 6) << 5) + (_R & 31);                            \
            _Pragma("unroll")                                                        \
            for (int _k = 0; _k < 2; ++_k) {                                         \
                const int _s = (_k * 4 + lk) ^ lx;                                   \
                dst[_n][_k] = *(const bf16x8*)&lds[(bb) * 32768 + 16384 +            \
                                                   _h * 8192 + _Lr * 64 + _s * 8];   \
            }                                                                        \
        }                                                                            \
    } while (0)

    #define MFMA16(AF, BF, MB, NB) do {                                              \
        __builtin_amdgcn_s_setprio(1);                                               \
        _Pragma("unroll")                                                            \
        for (int _m = 0; _m < 4; ++_m)                                               \
            _Pragma("unroll")                                                        \
            for (int _n = 0; _n < 2; ++_n)                                           \
                _Pragma("unroll")                                                    \
                for (int _k = 0; _k < 2; ++_k)                                       \
                    acc[(MB) + _m][(NB) + _n] =                                      \
                        __builtin_amdgcn_mfma_f32_16x16x32_bf16(                     \
                            AF[_m][_k], BF[_n][_k], acc[(MB) + _m][(NB) + _n], 0, 0, 0); \
        __builtin_amdgcn_s_setprio(0);                                               \
    } while (0)

    bf16x8 af[4][2], bfa[2][2], bfb[2][2];

    // ---- prologue: stage kt0 {Aa,Ba,Bb,Ab}; drain Aa0,Ba0 ----
    STAGE(Xrb, 0, 0, 0);              // A-alpha(0)
    STAGE(Wrb, 0, 0, 16384);          // B-alpha(0)
    STAGE(Wrb, 0, 1, 16384 + 8192);   // B-beta(0)
    STAGE(Xrb, 0, 1, 8192);           // A-beta(0)
    VMCNT4();
    __builtin_amdgcn_s_barrier();

    #pragma unroll 1
    for (int kt = 0; kt < 15; ++kt) {
        const int b = kt & 1, nb = b ^ 1;
        const int nbo = nb * 32768;
        // P1: read Aa(m0-3)+Ba(n0-1); stage Ba(kt+1)
        RD_A(af, 0, b);
        RD_B(bfa, 0, b);
        STAGE(Wrb, kt + 1, 0, nbo + 16384);
        VMCNT4();
        __builtin_amdgcn_s_barrier();
        LGKM0();
        MFMA16(af, bfa, 0, 0);
        // P2: read Bb(n2-3); stage Aa(kt+1)
        RD_B(bfb, 2, b);
        STAGE(Xrb, kt + 1, 0, nbo);
        VMCNT4();
        __builtin_amdgcn_s_barrier();
        LGKM0();
        MFMA16(af, bfb, 0, 2);
        // P3: read Ab(m4-7); stage Bb(kt+1)
        RD_A(af, 4, b);
        STAGE(Wrb, kt + 1, 1, nbo + 16384 + 8192);
        VMCNT4();
        __builtin_amdgcn_s_barrier();
        LGKM0();
        MFMA16(af, bfb, 4, 2);
        // P4: re-read Ba(n0-1); stage Ab(kt+1)
        RD_B(bfa, 0, b);
        STAGE(Xrb, kt + 1, 1, nbo + 8192);
        VMCNT4();
        __builtin_amdgcn_s_barrier();
        LGKM0();
        MFMA16(af, bfa, 4, 0);
    }
    // ---- tail kt=15 (buf 1, no staging) ----
    {
        RD_A(af, 0, 1);
        RD_B(bfa, 0, 1);
        VMCNT2();
        __builtin_amdgcn_s_barrier();
        LGKM0();
        MFMA16(af, bfa, 0, 0);
        RD_B(bfb, 2, 1);
        VMCNT0();
        __builtin_amdgcn_s_barrier();
        LGKM0();
        MFMA16(af, bfb, 0, 2);
        RD_A(af, 4, 1);
        LGKM0();
        MFMA16(af, bfb, 4, 2);
        RD_B(bfa, 0, 1);
        LGKM0();
        MFMA16(af, bfa, 4, 0);
    }

    // ---- epilogue: fused argmin-gather + bias; u32 best loads ----
    const int nbase = n0 + wr * 128 + lk * 4;
    #pragma unroll
    for (int nf = 0; nf < 4; ++nf) {
        const int opcol = col0 + wc * 64 + nf * 16 + lr;
        const int o = opcol >> 3;
        const unsigned p = (unsigned)(opcol & 7);
        const float bv = bias[opcol];
        const unsigned char* brow = best + (size_t)o * N_ + nbase;
        #pragma unroll
        for (int m = 0; m < 8; ++m) {
            const unsigned b4 = *(const unsigned*)(brow + m * 16);
            #pragma unroll
            for (int j = 0; j < 4; ++j) {
                if (((b4 >> (j * 8)) & 255u) == p) {
                    const int n = nbase + m * 16 + j;
                    out[(size_t)n * O_ + o] = acc[m][nf][j] + bv;
                }
            }
        }
    }
    #undef STAGE
    #undef RD_A
    #undef RD_B
    #undef MFMA16
    #undef VMCNT4
    #undef VMCNT2
    #undef VMCNT0
    #undef LGKM0
}

// ---------------------------------------------------------------------------
extern "C" void kernel_launch(void* const* d_in, const int* in_sizes, int n_in,
                              void* d_out, int out_size, void* d_ws, size_t ws_size,
                              hipStream_t stream) {
    const float* X      = (const float*)d_in[0];
    const float* ctx    = (const float*)d_in[1];
    const float* W      = (const float*)d_in[2];
    const float* bias   = (const float*)d_in[3];
    const float* protos = (const float*)d_in[4];
    float* out = (float*)d_out;

    char* ws = (char*)d_ws;
    unsigned char* best = (unsigned char*)ws;                         // 8 MiB
    float* psq = (float*)(ws + ((size_t)8 << 20));                    // 32 KiB
    unsigned short* Xb = (unsigned short*)(ws + ((size_t)9 << 20));   // 16 MiB
    unsigned short* Wb = (unsigned short*)(ws + ((size_t)25 << 20));  // 16 MiB
    unsigned* wl_cnt = (unsigned*)(ws + ((size_t)41 << 20));          // 4 B

    // scratch in d_out (fully overwritten by gemm later)
    char* ob = (char*)d_out;
    unsigned short* ph = (unsigned short*)(ob + ((size_t)16 << 20));  // 1 MiB
    unsigned short* pl = (unsigned short*)(ob + ((size_t)17 << 20));  // 1 MiB
    unsigned short* ch = (unsigned short*)(ob + ((size_t)18 << 20));  // 1 MiB
    unsigned short* cl = (unsigned short*)(ob + ((size_t)19 << 20));  // 1 MiB
    unsigned* wl = (unsigned*)(ob + ((size_t)20 << 20));              // 8 MiB (2M entries)

    hipFuncSetAttribute((const void*)gemm_gather_kernel,
                        hipFuncAttributeMaxDynamicSharedMemorySize, 131072);

    hipMemsetAsync(wl_cnt, 0, 4, stream);
    convert_tiled_kernel<0><<<dim3(4096), dim3(256), 0, stream>>>(X, Xb);
    convert_tiled_kernel<1><<<dim3(4096), dim3(256), 0, stream>>>(W, Wb);
    psq_kernel<<<dim3(32), dim3(256), 0, stream>>>(protos, psq);
    split_bf16_kernel<<<dim3(256), dim3(256), 0, stream>>>(protos, ph, pl);
    split_bf16_kernel<<<dim3(256), dim3(256), 0, stream>>>(ctx, ch, cl);
    argmin_mfma_kernel<<<dim3(OP_ / 128, N_ / 128), dim3(256), 0, stream>>>(ph, pl, ch, cl, psq, best);
    compact_kernel<<<dim3(8192), dim3(256), 0, stream>>>((const unsigned*)best, wl, wl_cnt);
    refine_wl_kernel<<<dim3(1024), dim3(256), 0, stream>>>(ctx, protos, wl, wl_cnt, best);
    gemm_gather_kernel<<<dim3(1024), dim3(512), 131072, stream>>>(Xb, Wb, bias, best, out);
}

// Round 10
// 329.596 us; speedup vs baseline: 3.5062x; 1.9572x over previous
//
#include <hip/hip_runtime.h>
#include <hip/hip_bf16.h>

#define N_ 8192
#define I_ 1024
#define O_ 1024
#define P_ 8
#define C_ 64
#define OP_ (O_ * P_)

typedef float f32x4 __attribute__((ext_vector_type(4)));
typedef __bf16 bf16x8 __attribute__((ext_vector_type(8)));
typedef unsigned short ushort8 __attribute__((ext_vector_type(8)));

#define GLOBAL_AS(p) ((const __attribute__((address_space(1))) unsigned int*)(p))
#define LDS_AS(p) ((__attribute__((address_space(3))) unsigned int*)(p))

// ---------------------------------------------------------------------------
// Kernel A0: proto_sq[o*8+p] = sum_c protos[o,p,c]^2  (fp32, exact)
// ---------------------------------------------------------------------------
__global__ void psq_kernel(const float* __restrict__ protos, float* __restrict__ psq) {
    const int idx = blockIdx.x * 256 + threadIdx.x;  // 0..8191
    const float* pr = protos + (size_t)idx * C_;
    float s = 0.f;
    #pragma unroll
    for (int c = 0; c < C_; ++c) s = fmaf(pr[c], pr[c], s);
    psq[idx] = s;
}

// ---------------------------------------------------------------------------
// Kernel S: split fp32 -> bf16 hi + lo (x = hi + lo + O(2^-17 x)).
// ---------------------------------------------------------------------------
__global__ __launch_bounds__(256)
void split_bf16_kernel(const float* __restrict__ src, unsigned short* __restrict__ hi,
                       unsigned short* __restrict__ lo) {
    const int idx = blockIdx.x * 256 + threadIdx.x;
    const float* sp = src + (size_t)idx * 8;
    const float4 f0 = *(const float4*)(sp);
    const float4 f1 = *(const float4*)(sp + 4);
    float f[8] = {f0.x, f0.y, f0.z, f0.w, f1.x, f1.y, f1.z, f1.w};
    ushort8 vh, vl;
    #pragma unroll
    for (int e = 0; e < 8; ++e) {
        const __hip_bfloat16 h = __float2bfloat16(f[e]);
        const __hip_bfloat16 l = __float2bfloat16(f[e] - __bfloat162float(h));
        vh[e] = __builtin_bit_cast(unsigned short, h);
        vl[e] = __builtin_bit_cast(unsigned short, l);
    }
    *(ushort8*)(hi + (size_t)idx * 8) = vh;
    *(ushort8*)(lo + (size_t)idx * 8) = vl;
}

// ---------------------------------------------------------------------------
// Kernel A: argmin via split-bf16 MFMA (validated round 8). Near-ties
// flagged in-place via bit 7 of best; static-index epilogue.
// ---------------------------------------------------------------------------
__global__ __launch_bounds__(256, 2)
void argmin_mfma_kernel(const unsigned short* __restrict__ ph, const unsigned short* __restrict__ pl,
                        const unsigned short* __restrict__ ch, const unsigned short* __restrict__ cl,
                        const float* __restrict__ psq, unsigned char* __restrict__ best) {
    const int tid = threadIdx.x;
    const int w = tid >> 6, l = tid & 63;
    const int op0 = blockIdx.x * 128;
    const int nw = blockIdx.y * 128 + w * 32;
    const int lr = l & 15, lk = l >> 4;

    f32x4 acc[8][2];
    #pragma unroll
    for (int of = 0; of < 8; ++of)
        #pragma unroll
        for (int nf = 0; nf < 2; ++nf) acc[of][nf] = (f32x4)(0.f);

    #pragma unroll
    for (int ks = 0; ks < 2; ++ks) {
        const int ko = ks * 32 + lk * 8;
        bf16x8 Ah[8], Al[8], Bh[2], Bl[2];
        #pragma unroll
        for (int of = 0; of < 8; ++of) {
            const size_t r = (size_t)(op0 + of * 16 + lr) * C_ + ko;
            Ah[of] = *(const bf16x8*)(ph + r);
            Al[of] = *(const bf16x8*)(pl + r);
        }
        #pragma unroll
        for (int nf = 0; nf < 2; ++nf) {
            const size_t r = (size_t)(nw + nf * 16 + lr) * C_ + ko;
            Bh[nf] = *(const bf16x8*)(ch + r);
            Bl[nf] = *(const bf16x8*)(cl + r);
        }
        #pragma unroll
        for (int of = 0; of < 8; ++of)
            #pragma unroll
            for (int nf = 0; nf < 2; ++nf) {
                acc[of][nf] = __builtin_amdgcn_mfma_f32_16x16x32_bf16(Ah[of], Bh[nf], acc[of][nf], 0, 0, 0);
                acc[of][nf] = __builtin_amdgcn_mfma_f32_16x16x32_bf16(Ah[of], Bl[nf], acc[of][nf], 0, 0, 0);
                acc[of][nf] = __builtin_amdgcn_mfma_f32_16x16x32_bf16(Al[of], Bh[nf], acc[of][nf], 0, 0, 0);
            }
    }

    #pragma unroll
    for (int of = 0; of < 8; ++of) {
        const int oprow0 = op0 + of * 16;
        const f32x4 ps = *(const f32x4*)(psq + oprow0 + lk * 4);
        #pragma unroll
        for (int nf = 0; nf < 2; ++nf) {
            const float d0 = fmaf(-2.f, acc[of][nf][0], ps[0]);
            const float d1 = fmaf(-2.f, acc[of][nf][1], ps[1]);
            const float d2 = fmaf(-2.f, acc[of][nf][2], ps[2]);
            const float d3 = fmaf(-2.f, acc[of][nf][3], ps[3]);
            const float e0 = __shfl_xor(d0, 16, 64);
            const float e1 = __shfl_xor(d1, 16, 64);
            const float e2 = __shfl_xor(d2, 16, 64);
            const float e3 = __shfl_xor(d3, 16, 64);
            float b1v = 3.4e38f, b2v = 3.4e38f;
            int bi = 0;
            #define UPD(val, pidx) do { const float _f = (val);                       \
                if (_f < b1v) { b2v = b1v; b1v = _f; bi = (pidx); }                   \
                else if (_f < b2v) b2v = _f; } while (0)
            UPD(d0, 0); UPD(d1, 1); UPD(d2, 2); UPD(d3, 3);
            UPD(e0, 4); UPD(e1, 5); UPD(e2, 6); UPD(e3, 7);
            #undef UPD
            if ((lk & 1) == 0) {
                const int o = (oprow0 >> 3) + (lk >> 1);
                const int n = nw + nf * 16 + lr;
                const unsigned flag = (b2v - b1v < 0.03f) ? 0x80u : 0u;
                best[(size_t)o * N_ + n] = (unsigned char)((unsigned)bi | flag);
            }
        }
    }
}

// ---------------------------------------------------------------------------
// Kernel A1.5: hierarchical compaction. 8 words (32 B)/thread, wave shfl
// scan + cross-wave LDS scan + ONE atomicAdd per BLOCK (1024 total).
// ---------------------------------------------------------------------------
__global__ __launch_bounds__(256)
void compact_kernel(const uint4* __restrict__ bw4, unsigned* __restrict__ wl,
                    unsigned* __restrict__ wl_cnt) {
    __shared__ unsigned wsum[4];
    const int tid = threadIdx.x;
    const int gidx = blockIdx.x * 256 + tid;      // 256K threads
    const uint4 v0 = bw4[(size_t)gidx * 2];
    const uint4 v1 = bw4[(size_t)gidx * 2 + 1];
    const unsigned words[8] = {v0.x, v0.y, v0.z, v0.w, v1.x, v1.y, v1.z, v1.w};
    unsigned k = 0;
    #pragma unroll
    for (int i = 0; i < 8; ++i) k += (unsigned)__popc(words[i] & 0x80808080u);

    const int lane = tid & 63;
    const int wv = tid >> 6;
    unsigned s = k;
    #pragma unroll
    for (int d = 1; d < 64; d <<= 1) {
        const unsigned t = __shfl_up(s, d, 64);
        if (lane >= d) s += t;
    }
    if (lane == 63) wsum[wv] = s;
    __syncthreads();
    if (tid == 0) {
        const unsigned t0 = wsum[0], t1 = wsum[1], t2 = wsum[2], t3 = wsum[3];
        const unsigned tot = t0 + t1 + t2 + t3;
        const unsigned base = tot ? atomicAdd(wl_cnt, tot) : 0u;
        wsum[0] = base;
        wsum[1] = base + t0;
        wsum[2] = base + t0 + t1;
        wsum[3] = base + t0 + t1 + t2;
    }
    __syncthreads();
    unsigned my = wsum[wv] + s - k;
    if (k) {
        #pragma unroll
        for (int i = 0; i < 8; ++i) {
            const unsigned fl = words[i] & 0x80808080u;
            if (!fl) continue;
            #pragma unroll
            for (int bq = 0; bq < 4; ++bq) {
                if ((fl >> (8 * bq + 7)) & 1u)
                    wl[my++] = (unsigned)gidx * 32u + (unsigned)(i * 4 + bq);
            }
        }
    }
}

// ---------------------------------------------------------------------------
// Kernel A2: parallel exact fp64 refine (validated round 9). 8 lanes per
// flagged element; shfl_xor argmin reduce with first-min tie-break.
// ---------------------------------------------------------------------------
__global__ __launch_bounds__(256)
void refine_wl_kernel(const float* __restrict__ ctx, const float* __restrict__ protos,
                      const unsigned* __restrict__ wl, const unsigned* __restrict__ wl_cnt,
                      unsigned char* __restrict__ best) {
    const unsigned cnt = *wl_cnt;
    const int lane8 = threadIdx.x & 7;
    const unsigned gid = (unsigned)(blockIdx.x * 256 + threadIdx.x) >> 3;
    const unsigned stride = (gridDim.x * 256) >> 3;
    for (unsigned i = gid; i < cnt; i += stride) {
        const unsigned off = wl[i];
        const int n = (int)(off & (N_ - 1));
        const int o = (int)(off >> 13);
        const float* cr = ctx + (size_t)n * C_;
        const float* pr = protos + ((size_t)o * 8 + lane8) * C_;
        double s = 0.0;
        #pragma unroll 8
        for (int c = 0; c < C_; ++c) {
            const double pv = (double)pr[c];
            const double cv = (double)cr[c];
            s += pv * (pv - 2.0 * cv);
        }
        int bi = lane8;
        #pragma unroll
        for (int d = 1; d < 8; d <<= 1) {
            const double s2 = __shfl_xor(s, d, 64);
            const int b2 = __shfl_xor(bi, d, 64);
            if (s2 < s || (s2 == s && b2 < bi)) { s = s2; bi = b2; }
        }
        if (lane8 == 0) best[off] = (unsigned char)bi;
    }
}

// ---------------------------------------------------------------------------
// Kernel C: fp32 -> bf16 into half-tile-blocked, row-XOR-swizzled layout
// (validated round 7).
// ---------------------------------------------------------------------------
template<int LAYOUT>
__global__ __launch_bounds__(256)
void convert_tiled_kernel(const float* __restrict__ src, unsigned short* __restrict__ dst) {
    const int idx = blockIdx.x * 256 + threadIdx.x;  // 1,048,576 chunks
    const int rb = idx >> 15;
    const int r = idx & 32767;
    const int kt = r >> 11;
    const int h = (r >> 10) & 1;
    const int L = r & 1023;
    const int Lr = L >> 3;
    const int j = L & 7;
    const int c = j ^ (Lr & 7);
    int Rlocal;
    if (LAYOUT == 0) Rlocal = (Lr & 63) + ((Lr & 64) << 1) + h * 64;
    else             Rlocal = ((Lr >> 5) << 6) + h * 32 + (Lr & 31);
    const int gR = rb * 256 + Rlocal;
    const int k0 = kt * 64 + c * 8;
    const float* sp = src + (size_t)gR * I_ + k0;
    const float4 f0 = *(const float4*)(sp);
    const float4 f1 = *(const float4*)(sp + 4);
    ushort8 v;
    v[0] = __builtin_bit_cast(unsigned short, __float2bfloat16(f0.x));
    v[1] = __builtin_bit_cast(unsigned short, __float2bfloat16(f0.y));
    v[2] = __builtin_bit_cast(unsigned short, __float2bfloat16(f0.z));
    v[3] = __builtin_bit_cast(unsigned short, __float2bfloat16(f0.w));
    v[4] = __builtin_bit_cast(unsigned short, __float2bfloat16(f1.x));
    v[5] = __builtin_bit_cast(unsigned short, __float2bfloat16(f1.y));
    v[6] = __builtin_bit_cast(unsigned short, __float2bfloat16(f1.z));
    v[7] = __builtin_bit_cast(unsigned short, __float2bfloat16(f1.w));
    *(ushort8*)(dst + (size_t)idx * 8) = v;
}

// ---------------------------------------------------------------------------
// Kernel B: 256x256 phase-pipelined bf16 MFMA GEMM (validated round 7) +
// fused argmin-gather epilogue.
// ---------------------------------------------------------------------------
__global__ __launch_bounds__(512, 1)
void gemm_gather_kernel(const unsigned short* __restrict__ Xb,
                        const unsigned short* __restrict__ Wb,
                        const float* __restrict__ bias,
                        const unsigned char* __restrict__ best,
                        float* __restrict__ out) {
    extern __shared__ unsigned short lds[];  // 2 x (A 16384 + B 16384) ushort = 128 KiB

    int wg = blockIdx.x;                     // 1024 blocks, %8==0 -> bijective
    wg = (wg & 7) * 128 + (wg >> 3);
    const int bx = wg & 31;
    const int by = wg >> 5;
    const int n0 = by * 256;
    const int col0 = bx * 256;

    const int tid = threadIdx.x;
    const int w = tid >> 6, l = tid & 63;
    const int wr = w >> 2, wc = w & 3;
    const int lr = l & 15, lk = l >> 4;
    const int lx = lr & 7;

    const unsigned short* Xrb = Xb + (size_t)(n0 >> 8) * 262144;
    const unsigned short* Wrb = Wb + (size_t)(col0 >> 8) * 262144;

    #define STAGE(src, ktt, h, ldsofs) do {                                          \
        const unsigned short* _g = (src) + ((size_t)(ktt) * 2 + (h)) * 8192;         \
        __builtin_amdgcn_global_load_lds(GLOBAL_AS(_g + (size_t)tid * 8),            \
            LDS_AS(lds + (ldsofs) + tid * 8), 16, 0, 0);                             \
        __builtin_amdgcn_global_load_lds(GLOBAL_AS(_g + (size_t)(tid + 512) * 8),    \
            LDS_AS(lds + (ldsofs) + (tid + 512) * 8), 16, 0, 0);                     \
    } while (0)

    #define VMCNT4() do { asm volatile("s_waitcnt vmcnt(4)" ::: "memory");           \
        __builtin_amdgcn_sched_barrier(0); } while (0)
    #define VMCNT2() do { asm volatile("s_waitcnt vmcnt(2)" ::: "memory");           \
        __builtin_amdgcn_sched_barrier(0); } while (0)
    #define VMCNT0() do { asm volatile("s_waitcnt vmcnt(0)" ::: "memory");           \
        __builtin_amdgcn_sched_barrier(0); } while (0)
    #define LGKM0() do { asm volatile("s_waitcnt lgkmcnt(0)" ::: "memory");          \
        __builtin_amdgcn_sched_barrier(0); } while (0)

    f32x4 acc[8][4];
    #pragma unroll
    for (int m = 0; m < 8; ++m)
        #pragma unroll
        for (int n = 0; n < 4; ++n) acc[m][n] = (f32x4)(0.f);

    #define RD_A(dst, mbase, bb) do {                                                \
        _Pragma("unroll")                                                            \
        for (int _m = 0; _m < 4; ++_m) {                                             \
            const int _R = wr * 128 + ((mbase) + _m) * 16 + lr;                      \
            const int _h = (_R >> 6) & 1;                                            \
            const int _Lr = (_R & 63) + ((_R & 128) >> 1);                           \
            _Pragma("unroll")                                                        \
            for (int _k = 0; _k < 2; ++_k) {                                         \
                const int _s = (_k * 4 + lk) ^ lx;                                   \
                dst[_m][_k] = *(const bf16x8*)&lds[(bb) * 32768 + _h * 8192 +        \
                                                   _Lr * 64 + _s * 8];               \
            }                                                                        \
        }                                                                            \
    } while (0)

    #define RD_B(dst, nbase, bb) do {                                                \
        _Pragma("unroll")                                                            \
        for (int _n = 0; _n < 2; ++_n) {                                             \
            const int _R = wc * 64 + ((nbase) + _n) * 16 + lr;                       \
            const int _h = (_R >> 5) & 1;                                            \
            const int _Lr = ((_R >> 6) << 5) + (_R & 31);                            \
            _Pragma("unroll")                                                        \
            for (int _k = 0; _k < 2; ++_k) {                                         \
                const int _s = (_k * 4 + lk) ^ lx;                                   \
                dst[_n][_k] = *(const bf16x8*)&lds[(bb) * 32768 + 16384 +            \
                                                   _h * 8192 + _Lr * 64 + _s * 8];   \
            }                                                                        \
        }                                                                            \
    } while (0)

    #define MFMA16(AF, BF, MB, NB) do {                                              \
        __builtin_amdgcn_s_setprio(1);                                               \
        _Pragma("unroll")                                                            \
        for (int _m = 0; _m < 4; ++_m)                                               \
            _Pragma("unroll")                                                        \
            for (int _n = 0; _n < 2; ++_n)                                           \
                _Pragma("unroll")                                                    \
                for (int _k = 0; _k < 2; ++_k)                                       \
                    acc[(MB) + _m][(NB) + _n] =                                      \
                        __builtin_amdgcn_mfma_f32_16x16x32_bf16(                     \
                            AF[_m][_k], BF[_n][_k], acc[(MB) + _m][(NB) + _n], 0, 0, 0); \
        __builtin_amdgcn_s_setprio(0);                                               \
    } while (0)

    bf16x8 af[4][2], bfa[2][2], bfb[2][2];

    // ---- prologue: stage kt0 {Aa,Ba,Bb,Ab}; drain Aa0,Ba0 ----
    STAGE(Xrb, 0, 0, 0);              // A-alpha(0)
    STAGE(Wrb, 0, 0, 16384);          // B-alpha(0)
    STAGE(Wrb, 0, 1, 16384 + 8192);   // B-beta(0)
    STAGE(Xrb, 0, 1, 8192);           // A-beta(0)
    VMCNT4();
    __builtin_amdgcn_s_barrier();

    #pragma unroll 1
    for (int kt = 0; kt < 15; ++kt) {
        const int b = kt & 1, nb = b ^ 1;
        const int nbo = nb * 32768;
        // P1: read Aa(m0-3)+Ba(n0-1); stage Ba(kt+1)
        RD_A(af, 0, b);
        RD_B(bfa, 0, b);
        STAGE(Wrb, kt + 1, 0, nbo + 16384);
        VMCNT4();
        __builtin_amdgcn_s_barrier();
        LGKM0();
        MFMA16(af, bfa, 0, 0);
        // P2: read Bb(n2-3); stage Aa(kt+1)
        RD_B(bfb, 2, b);
        STAGE(Xrb, kt + 1, 0, nbo);
        VMCNT4();
        __builtin_amdgcn_s_barrier();
        LGKM0();
        MFMA16(af, bfb, 0, 2);
        // P3: read Ab(m4-7); stage Bb(kt+1)
        RD_A(af, 4, b);
        STAGE(Wrb, kt + 1, 1, nbo + 16384 + 8192);
        VMCNT4();
        __builtin_amdgcn_s_barrier();
        LGKM0();
        MFMA16(af, bfb, 4, 2);
        // P4: re-read Ba(n0-1); stage Ab(kt+1)
        RD_B(bfa, 0, b);
        STAGE(Xrb, kt + 1, 1, nbo + 8192);
        VMCNT4();
        __builtin_amdgcn_s_barrier();
        LGKM0();
        MFMA16(af, bfa, 4, 0);
    }
    // ---- tail kt=15 (buf 1, no staging) ----
    {
        RD_A(af, 0, 1);
        RD_B(bfa, 0, 1);
        VMCNT2();
        __builtin_amdgcn_s_barrier();
        LGKM0();
        MFMA16(af, bfa, 0, 0);
        RD_B(bfb, 2, 1);
        VMCNT0();
        __builtin_amdgcn_s_barrier();
        LGKM0();
        MFMA16(af, bfb, 0, 2);
        RD_A(af, 4, 1);
        LGKM0();
        MFMA16(af, bfb, 4, 2);
        RD_B(bfa, 0, 1);
        LGKM0();
        MFMA16(af, bfa, 4, 0);
    }

    // ---- epilogue: fused argmin-gather + bias; u32 best loads ----
    const int nbase = n0 + wr * 128 + lk * 4;
    #pragma unroll
    for (int nf = 0; nf < 4; ++nf) {
        const int opcol = col0 + wc * 64 + nf * 16 + lr;
        const int o = opcol >> 3;
        const unsigned p = (unsigned)(opcol & 7);
        const float bv = bias[opcol];
        const unsigned char* brow = best + (size_t)o * N_ + nbase;
        #pragma unroll
        for (int m = 0; m < 8; ++m) {
            const unsigned b4 = *(const unsigned*)(brow + m * 16);
            #pragma unroll
            for (int j = 0; j < 4; ++j) {
                if (((b4 >> (j * 8)) & 255u) == p) {
                    const int n = nbase + m * 16 + j;
                    out[(size_t)n * O_ + o] = acc[m][nf][j] + bv;
                }
            }
        }
    }
    #undef STAGE
    #undef RD_A
    #undef RD_B
    #undef MFMA16
    #undef VMCNT4
    #undef VMCNT2
    #undef VMCNT0
    #undef LGKM0
}

// ---------------------------------------------------------------------------
extern "C" void kernel_launch(void* const* d_in, const int* in_sizes, int n_in,
                              void* d_out, int out_size, void* d_ws, size_t ws_size,
                              hipStream_t stream) {
    const float* X      = (const float*)d_in[0];
    const float* ctx    = (const float*)d_in[1];
    const float* W      = (const float*)d_in[2];
    const float* bias   = (const float*)d_in[3];
    const float* protos = (const float*)d_in[4];
    float* out = (float*)d_out;

    char* ws = (char*)d_ws;
    unsigned char* best = (unsigned char*)ws;                         // 8 MiB
    float* psq = (float*)(ws + ((size_t)8 << 20));                    // 32 KiB
    unsigned short* Xb = (unsigned short*)(ws + ((size_t)9 << 20));   // 16 MiB
    unsigned short* Wb = (unsigned short*)(ws + ((size_t)25 << 20));  // 16 MiB
    unsigned* wl_cnt = (unsigned*)(ws + ((size_t)41 << 20));          // 4 B

    // scratch in d_out (fully overwritten by gemm later)
    char* ob = (char*)d_out;
    unsigned short* ph = (unsigned short*)(ob + ((size_t)16 << 20));  // 1 MiB
    unsigned short* pl = (unsigned short*)(ob + ((size_t)17 << 20));  // 1 MiB
    unsigned short* ch = (unsigned short*)(ob + ((size_t)18 << 20));  // 1 MiB
    unsigned short* cl = (unsigned short*)(ob + ((size_t)19 << 20));  // 1 MiB
    unsigned* wl = (unsigned*)(ob + ((size_t)20 << 20));              // 8 MiB (2M entries)

    hipFuncSetAttribute((const void*)gemm_gather_kernel,
                        hipFuncAttributeMaxDynamicSharedMemorySize, 131072);

    hipMemsetAsync(wl_cnt, 0, 4, stream);
    convert_tiled_kernel<0><<<dim3(4096), dim3(256), 0, stream>>>(X, Xb);
    convert_tiled_kernel<1><<<dim3(4096), dim3(256), 0, stream>>>(W, Wb);
    psq_kernel<<<dim3(32), dim3(256), 0, stream>>>(protos, psq);
    split_bf16_kernel<<<dim3(256), dim3(256), 0, stream>>>(protos, ph, pl);
    split_bf16_kernel<<<dim3(256), dim3(256), 0, stream>>>(ctx, ch, cl);
    argmin_mfma_kernel<<<dim3(OP_ / 128, N_ / 128), dim3(256), 0, stream>>>(ph, pl, ch, cl, psq, best);
    compact_kernel<<<dim3(1024), dim3(256), 0, stream>>>((const uint4*)best, wl, wl_cnt);
    refine_wl_kernel<<<dim3(1024), dim3(256), 0, stream>>>(ctx, protos, wl, wl_cnt, best);
    gemm_gather_kernel<<<dim3(1024), dim3(512), 131072, stream>>>(Xb, Wb, bias, best, out);
}

// Round 11
// 328.870 us; speedup vs baseline: 3.5139x; 1.0022x over previous
//
#include <hip/hip_runtime.h>
#include <hip/hip_bf16.h>

#define N_ 8192
#define I_ 1024
#define O_ 1024
#define P_ 8
#define C_ 64
#define OP_ (O_ * P_)

typedef float f32x4 __attribute__((ext_vector_type(4)));
typedef __bf16 bf16x8 __attribute__((ext_vector_type(8)));
typedef unsigned short ushort8 __attribute__((ext_vector_type(8)));

#define GLOBAL_AS(p) ((const __attribute__((address_space(1))) unsigned int*)(p))
#define LDS_AS(p) ((__attribute__((address_space(3))) unsigned int*)(p))

// ---------------------------------------------------------------------------
// Kernel P: fused prep. Blocks 0-255: split protos -> ph,pl. 256-511: split
// ctx -> ch,cl. 512-543: psq.  (split: x = hi + lo, both bf16)
// ---------------------------------------------------------------------------
__global__ __launch_bounds__(256)
void prep_kernel(const float* __restrict__ protos, const float* __restrict__ ctx,
                 unsigned short* __restrict__ ph, unsigned short* __restrict__ pl,
                 unsigned short* __restrict__ ch, unsigned short* __restrict__ cl,
                 float* __restrict__ psq) {
    const int b = blockIdx.x;
    if (b < 512) {
        const float* src = (b < 256) ? protos : ctx;
        unsigned short* hi = (b < 256) ? ph : ch;
        unsigned short* lo = (b < 256) ? pl : cl;
        const int idx = (b & 255) * 256 + threadIdx.x;
        const float* sp = src + (size_t)idx * 8;
        const float4 f0 = *(const float4*)(sp);
        const float4 f1 = *(const float4*)(sp + 4);
        float f[8] = {f0.x, f0.y, f0.z, f0.w, f1.x, f1.y, f1.z, f1.w};
        ushort8 vh, vl;
        #pragma unroll
        for (int e = 0; e < 8; ++e) {
            const __hip_bfloat16 h = __float2bfloat16(f[e]);
            const __hip_bfloat16 l = __float2bfloat16(f[e] - __bfloat162float(h));
            vh[e] = __builtin_bit_cast(unsigned short, h);
            vl[e] = __builtin_bit_cast(unsigned short, l);
        }
        *(ushort8*)(hi + (size_t)idx * 8) = vh;
        *(ushort8*)(lo + (size_t)idx * 8) = vl;
    } else {
        const int idx = (b - 512) * 256 + threadIdx.x;  // 0..8191
        const float* pr = protos + (size_t)idx * C_;
        float s = 0.f;
        #pragma unroll
        for (int c = 0; c < C_; ++c) s = fmaf(pr[c], pr[c], s);
        psq[idx] = s;
    }
}

// ---------------------------------------------------------------------------
// Kernel A: argmin via split-bf16 MFMA (validated rounds 8-10). Near-ties
// flagged in-place via bit 7 of best; static-index epilogue.
// ---------------------------------------------------------------------------
__global__ __launch_bounds__(256, 2)
void argmin_mfma_kernel(const unsigned short* __restrict__ ph, const unsigned short* __restrict__ pl,
                        const unsigned short* __restrict__ ch, const unsigned short* __restrict__ cl,
                        const float* __restrict__ psq, unsigned char* __restrict__ best) {
    const int tid = threadIdx.x;
    const int w = tid >> 6, l = tid & 63;
    const int op0 = blockIdx.x * 128;
    const int nw = blockIdx.y * 128 + w * 32;
    const int lr = l & 15, lk = l >> 4;

    f32x4 acc[8][2];
    #pragma unroll
    for (int of = 0; of < 8; ++of)
        #pragma unroll
        for (int nf = 0; nf < 2; ++nf) acc[of][nf] = (f32x4)(0.f);

    #pragma unroll
    for (int ks = 0; ks < 2; ++ks) {
        const int ko = ks * 32 + lk * 8;
        bf16x8 Ah[8], Al[8], Bh[2], Bl[2];
        #pragma unroll
        for (int of = 0; of < 8; ++of) {
            const size_t r = (size_t)(op0 + of * 16 + lr) * C_ + ko;
            Ah[of] = *(const bf16x8*)(ph + r);
            Al[of] = *(const bf16x8*)(pl + r);
        }
        #pragma unroll
        for (int nf = 0; nf < 2; ++nf) {
            const size_t r = (size_t)(nw + nf * 16 + lr) * C_ + ko;
            Bh[nf] = *(const bf16x8*)(ch + r);
            Bl[nf] = *(const bf16x8*)(cl + r);
        }
        #pragma unroll
        for (int of = 0; of < 8; ++of)
            #pragma unroll
            for (int nf = 0; nf < 2; ++nf) {
                acc[of][nf] = __builtin_amdgcn_mfma_f32_16x16x32_bf16(Ah[of], Bh[nf], acc[of][nf], 0, 0, 0);
                acc[of][nf] = __builtin_amdgcn_mfma_f32_16x16x32_bf16(Ah[of], Bl[nf], acc[of][nf], 0, 0, 0);
                acc[of][nf] = __builtin_amdgcn_mfma_f32_16x16x32_bf16(Al[of], Bh[nf], acc[of][nf], 0, 0, 0);
            }
    }

    #pragma unroll
    for (int of = 0; of < 8; ++of) {
        const int oprow0 = op0 + of * 16;
        const f32x4 ps = *(const f32x4*)(psq + oprow0 + lk * 4);
        #pragma unroll
        for (int nf = 0; nf < 2; ++nf) {
            const float d0 = fmaf(-2.f, acc[of][nf][0], ps[0]);
            const float d1 = fmaf(-2.f, acc[of][nf][1], ps[1]);
            const float d2 = fmaf(-2.f, acc[of][nf][2], ps[2]);
            const float d3 = fmaf(-2.f, acc[of][nf][3], ps[3]);
            const float e0 = __shfl_xor(d0, 16, 64);
            const float e1 = __shfl_xor(d1, 16, 64);
            const float e2 = __shfl_xor(d2, 16, 64);
            const float e3 = __shfl_xor(d3, 16, 64);
            float b1v = 3.4e38f, b2v = 3.4e38f;
            int bi = 0;
            #define UPD(val, pidx) do { const float _f = (val);                       \
                if (_f < b1v) { b2v = b1v; b1v = _f; bi = (pidx); }                   \
                else if (_f < b2v) b2v = _f; } while (0)
            UPD(d0, 0); UPD(d1, 1); UPD(d2, 2); UPD(d3, 3);
            UPD(e0, 4); UPD(e1, 5); UPD(e2, 6); UPD(e3, 7);
            #undef UPD
            if ((lk & 1) == 0) {
                const int o = (oprow0 >> 3) + (lk >> 1);
                const int n = nw + nf * 16 + lr;
                const unsigned flag = (b2v - b1v < 0.03f) ? 0x80u : 0u;
                best[(size_t)o * N_ + n] = (unsigned char)((unsigned)bi | flag);
            }
        }
    }
}

// ---------------------------------------------------------------------------
// Kernel A1.5: hierarchical compaction (validated round 10). One atomic/block.
// ---------------------------------------------------------------------------
__global__ __launch_bounds__(256)
void compact_kernel(const uint4* __restrict__ bw4, unsigned* __restrict__ wl,
                    unsigned* __restrict__ wl_cnt) {
    __shared__ unsigned wsum[4];
    const int tid = threadIdx.x;
    const int gidx = blockIdx.x * 256 + tid;
    const uint4 v0 = bw4[(size_t)gidx * 2];
    const uint4 v1 = bw4[(size_t)gidx * 2 + 1];
    const unsigned words[8] = {v0.x, v0.y, v0.z, v0.w, v1.x, v1.y, v1.z, v1.w};
    unsigned k = 0;
    #pragma unroll
    for (int i = 0; i < 8; ++i) k += (unsigned)__popc(words[i] & 0x80808080u);

    const int lane = tid & 63;
    const int wv = tid >> 6;
    unsigned s = k;
    #pragma unroll
    for (int d = 1; d < 64; d <<= 1) {
        const unsigned t = __shfl_up(s, d, 64);
        if (lane >= d) s += t;
    }
    if (lane == 63) wsum[wv] = s;
    __syncthreads();
    if (tid == 0) {
        const unsigned t0 = wsum[0], t1 = wsum[1], t2 = wsum[2], t3 = wsum[3];
        const unsigned tot = t0 + t1 + t2 + t3;
        const unsigned base = tot ? atomicAdd(wl_cnt, tot) : 0u;
        wsum[0] = base;
        wsum[1] = base + t0;
        wsum[2] = base + t0 + t1;
        wsum[3] = base + t0 + t1 + t2;
    }
    __syncthreads();
    unsigned my = wsum[wv] + s - k;
    if (k) {
        #pragma unroll
        for (int i = 0; i < 8; ++i) {
            const unsigned fl = words[i] & 0x80808080u;
            if (!fl) continue;
            #pragma unroll
            for (int bq = 0; bq < 4; ++bq) {
                if ((fl >> (8 * bq + 7)) & 1u)
                    wl[my++] = (unsigned)gidx * 32u + (unsigned)(i * 4 + bq);
            }
        }
    }
}

// ---------------------------------------------------------------------------
// Kernel A2: parallel exact fp64 refine (validated rounds 9-10).
// ---------------------------------------------------------------------------
__global__ __launch_bounds__(256)
void refine_wl_kernel(const float* __restrict__ ctx, const float* __restrict__ protos,
                      const unsigned* __restrict__ wl, const unsigned* __restrict__ wl_cnt,
                      unsigned char* __restrict__ best) {
    const unsigned cnt = *wl_cnt;
    const int lane8 = threadIdx.x & 7;
    const unsigned gid = (unsigned)(blockIdx.x * 256 + threadIdx.x) >> 3;
    const unsigned stride = (gridDim.x * 256) >> 3;
    for (unsigned i = gid; i < cnt; i += stride) {
        const unsigned off = wl[i];
        const int n = (int)(off & (N_ - 1));
        const int o = (int)(off >> 13);
        const float* cr = ctx + (size_t)n * C_;
        const float* pr = protos + ((size_t)o * 8 + lane8) * C_;
        double s = 0.0;
        #pragma unroll 8
        for (int c = 0; c < C_; ++c) {
            const double pv = (double)pr[c];
            const double cv = (double)cr[c];
            s += pv * (pv - 2.0 * cv);
        }
        int bi = lane8;
        #pragma unroll
        for (int d = 1; d < 8; d <<= 1) {
            const double s2 = __shfl_xor(s, d, 64);
            const int b2 = __shfl_xor(bi, d, 64);
            if (s2 < s || (s2 == s && b2 < bi)) { s = s2; bi = b2; }
        }
        if (lane8 == 0) best[off] = (unsigned char)bi;
    }
}

// ---------------------------------------------------------------------------
// Kernel C: fp32 -> bf16 into half-tile-blocked, row-XOR-swizzled layout
// (validated rounds 7-10).
// ---------------------------------------------------------------------------
template<int LAYOUT>
__global__ __launch_bounds__(256)
void convert_tiled_kernel(const float* __restrict__ src, unsigned short* __restrict__ dst) {
    const int idx = blockIdx.x * 256 + threadIdx.x;  // 1,048,576 chunks
    const int rb = idx >> 15;
    const int r = idx & 32767;
    const int kt = r >> 11;
    const int h = (r >> 10) & 1;
    const int L = r & 1023;
    const int Lr = L >> 3;
    const int j = L & 7;
    const int c = j ^ (Lr & 7);
    int Rlocal;
    if (LAYOUT == 0) Rlocal = (Lr & 63) + ((Lr & 64) << 1) + h * 64;
    else             Rlocal = ((Lr >> 5) << 6) + h * 32 + (Lr & 31);
    const int gR = rb * 256 + Rlocal;
    const int k0 = kt * 64 + c * 8;
    const float* sp = src + (size_t)gR * I_ + k0;
    const float4 f0 = *(const float4*)(sp);
    const float4 f1 = *(const float4*)(sp + 4);
    ushort8 v;
    v[0] = __builtin_bit_cast(unsigned short, __float2bfloat16(f0.x));
    v[1] = __builtin_bit_cast(unsigned short, __float2bfloat16(f0.y));
    v[2] = __builtin_bit_cast(unsigned short, __float2bfloat16(f0.z));
    v[3] = __builtin_bit_cast(unsigned short, __float2bfloat16(f0.w));
    v[4] = __builtin_bit_cast(unsigned short, __float2bfloat16(f1.x));
    v[5] = __builtin_bit_cast(unsigned short, __float2bfloat16(f1.y));
    v[6] = __builtin_bit_cast(unsigned short, __float2bfloat16(f1.z));
    v[7] = __builtin_bit_cast(unsigned short, __float2bfloat16(f1.w));
    *(ushort8*)(dst + (size_t)idx * 8) = v;
}

// ---------------------------------------------------------------------------
// Kernel B: 256x256 bf16 MFMA GEMM, m201-style counted-vmcnt schedule.
// Per phase: {RD, STAGE, [vmcnt], BAR, LGKM0, setprio MFMA setprio, BAR}.
// vmcnt ONLY twice per kt: vmcnt(4)@P4-end (completes Ba',Aa' for next P1,
// leaves Bb',Ab' in flight) and vmcnt(2)@P1-end (completes Bb,Ab for P2/P3,
// leaves P1's fresh stage untouched). No wait ever lands on a load younger
// than 3 phases. Stagger P1:Ba' P2:Aa' P3:Bb' P4:Ab' into dbuf partner;
// all restages >= 2 barriers after slot death (WAR-safe).
// ---------------------------------------------------------------------------
__global__ __launch_bounds__(512, 1)
void gemm_gather_kernel(const unsigned short* __restrict__ Xb,
                        const unsigned short* __restrict__ Wb,
                        const float* __restrict__ bias,
                        const unsigned char* __restrict__ best,
                        float* __restrict__ out) {
    extern __shared__ unsigned short lds[];  // 2 x (A 16384 + B 16384) ushort = 128 KiB

    int wg = blockIdx.x;                     // 1024 blocks, %8==0 -> bijective
    wg = (wg & 7) * 128 + (wg >> 3);
    const int bx = wg & 31;
    const int by = wg >> 5;
    const int n0 = by * 256;
    const int col0 = bx * 256;

    const int tid = threadIdx.x;
    const int w = tid >> 6, l = tid & 63;
    const int wr = w >> 2, wc = w & 3;
    const int lr = l & 15, lk = l >> 4;
    const int lx = lr & 7;

    const unsigned short* Xrb = Xb + (size_t)(n0 >> 8) * 262144;
    const unsigned short* Wrb = Wb + (size_t)(col0 >> 8) * 262144;

    #define STAGE(src, ktt, h, ldsofs) do {                                          \
        const unsigned short* _g = (src) + ((size_t)(ktt) * 2 + (h)) * 8192;         \
        __builtin_amdgcn_global_load_lds(GLOBAL_AS(_g + (size_t)tid * 8),            \
            LDS_AS(lds + (ldsofs) + tid * 8), 16, 0, 0);                             \
        __builtin_amdgcn_global_load_lds(GLOBAL_AS(_g + (size_t)(tid + 512) * 8),    \
            LDS_AS(lds + (ldsofs) + (tid + 512) * 8), 16, 0, 0);                     \
    } while (0)

    #define VMCNT4() do { asm volatile("s_waitcnt vmcnt(4)" ::: "memory");           \
        __builtin_amdgcn_sched_barrier(0); } while (0)
    #define VMCNT2() do { asm volatile("s_waitcnt vmcnt(2)" ::: "memory");           \
        __builtin_amdgcn_sched_barrier(0); } while (0)
    #define VMCNT0() do { asm volatile("s_waitcnt vmcnt(0)" ::: "memory");           \
        __builtin_amdgcn_sched_barrier(0); } while (0)
    #define LGKM0() do { asm volatile("s_waitcnt lgkmcnt(0)" ::: "memory");          \
        __builtin_amdgcn_sched_barrier(0); } while (0)
    #define BAR() __builtin_amdgcn_s_barrier()

    f32x4 acc[8][4];
    #pragma unroll
    for (int m = 0; m < 8; ++m)
        #pragma unroll
        for (int n = 0; n < 4; ++n) acc[m][n] = (f32x4)(0.f);

    #define RD_A(dst, mbase, bb) do {                                                \
        _Pragma("unroll")                                                            \
        for (int _m = 0; _m < 4; ++_m) {                                             \
            const int _R = wr * 128 + ((mbase) + _m) * 16 + lr;                      \
            const int _h = (_R >> 6) & 1;                                            \
            const int _Lr = (_R & 63) + ((_R & 128) >> 1);                           \
            _Pragma("unroll")                                                        \
            for (int _k = 0; _k < 2; ++_k) {                                         \
                const int _s = (_k * 4 + lk) ^ lx;                                   \
                dst[_m][_k] = *(const bf16x8*)&lds[(bb) * 32768 + _h * 8192 +        \
                                                   _Lr * 64 + _s * 8];               \
            }                                                                        \
        }                                                                            \
    } while (0)

    #define RD_B(dst, nbase, bb) do {                                                \
        _Pragma("unroll")                                                            \
        for (int _n = 0; _n < 2; ++_n) {                                             \
            const int _R = wc * 64 + ((nbase) + _n) * 16 + lr;                       \
            const int _h = (_R >> 5) & 1;                                            \
            const int _Lr = ((_R >> 6) << 5) + (_R & 31);                            \
            _Pragma("unroll")                                                        \
            for (int _k = 0; _k < 2; ++_k) {                                         \
                const int _s = (_k * 4 + lk) ^ lx;                                   \
                dst[_n][_k] = *(const bf16x8*)&lds[(bb) * 32768 + 16384 +            \
                                                   _h * 8192 + _Lr * 64 + _s * 8];   \
            }                                                                        \
        }                                                                            \
    } while (0)

    #define MFMA16(AF, BF, MB, NB) do {                                              \
        __builtin_amdgcn_s_setprio(1);                                               \
        _Pragma("unroll")                                                            \
        for (int _m = 0; _m < 4; ++_m)                                               \
            _Pragma("unroll")                                                        \
            for (int _n = 0; _n < 2; ++_n)                                           \
                _Pragma("unroll")                                                    \
                for (int _k = 0; _k < 2; ++_k)                                       \
                    acc[(MB) + _m][(NB) + _n] =                                      \
                        __builtin_amdgcn_mfma_f32_16x16x32_bf16(                     \
                            AF[_m][_k], BF[_n][_k], acc[(MB) + _m][(NB) + _n], 0, 0, 0); \
        __builtin_amdgcn_s_setprio(0);                                               \
    } while (0)

    bf16x8 af[4][2], bfa[2][2], bfb[2][2];

    // ---- prologue: stage kt0 {Aa,Ba,Bb,Ab}; vmcnt(4) completes Aa0,Ba0 ----
    STAGE(Xrb, 0, 0, 0);              // A-alpha(0)
    STAGE(Wrb, 0, 0, 16384);          // B-alpha(0)
    STAGE(Wrb, 0, 1, 16384 + 8192);   // B-beta(0)
    STAGE(Xrb, 0, 1, 8192);           // A-beta(0)
    VMCNT4();
    BAR();

    #pragma unroll 1
    for (int kt = 0; kt < 15; ++kt) {
        const int b = kt & 1, nb = b ^ 1;
        const int nbo = nb * 32768;
        // P1: RD Aa+Ba; stage Ba(kt+1); vmcnt(2) completes Bb(kt),Ab(kt)
        RD_A(af, 0, b);
        RD_B(bfa, 0, b);
        STAGE(Wrb, kt + 1, 0, nbo + 16384);
        VMCNT2();
        BAR();
        LGKM0();
        MFMA16(af, bfa, 0, 0);
        BAR();
        // P2: RD Bb; stage Aa(kt+1)
        RD_B(bfb, 2, b);
        STAGE(Xrb, kt + 1, 0, nbo);
        BAR();
        LGKM0();
        MFMA16(af, bfb, 0, 2);
        BAR();
        // P3: RD Ab; stage Bb(kt+1)
        RD_A(af, 4, b);
        STAGE(Wrb, kt + 1, 1, nbo + 16384 + 8192);
        BAR();
        LGKM0();
        MFMA16(af, bfb, 4, 2);
        BAR();
        // P4: re-RD Ba; stage Ab(kt+1); vmcnt(4) completes Ba(kt+1),Aa(kt+1)
        RD_B(bfa, 0, b);
        STAGE(Xrb, kt + 1, 1, nbo + 8192);
        VMCNT4();
        BAR();
        LGKM0();
        MFMA16(af, bfa, 4, 0);
        BAR();
    }
    // ---- tail kt=15 (buf 1, no staging; vmcnt(0) then barrier-free) ----
    {
        RD_A(af, 0, 1);
        RD_B(bfa, 0, 1);
        VMCNT0();
        BAR();
        LGKM0();
        MFMA16(af, bfa, 0, 0);
        BAR();
        RD_B(bfb, 2, 1);
        LGKM0();
        MFMA16(af, bfb, 0, 2);
        RD_A(af, 4, 1);
        LGKM0();
        MFMA16(af, bfb, 4, 2);
        RD_B(bfa, 0, 1);
        LGKM0();
        MFMA16(af, bfa, 4, 0);
    }

    // ---- epilogue: fused argmin-gather + bias; u32 best loads ----
    const int nbase = n0 + wr * 128 + lk * 4;
    #pragma unroll
    for (int nf = 0; nf < 4; ++nf) {
        const int opcol = col0 + wc * 64 + nf * 16 + lr;
        const int o = opcol >> 3;
        const unsigned p = (unsigned)(opcol & 7);
        const float bv = bias[opcol];
        const unsigned char* brow = best + (size_t)o * N_ + nbase;
        #pragma unroll
        for (int m = 0; m < 8; ++m) {
            const unsigned b4 = *(const unsigned*)(brow + m * 16);
            #pragma unroll
            for (int j = 0; j < 4; ++j) {
                if (((b4 >> (j * 8)) & 255u) == p) {
                    const int n = nbase + m * 16 + j;
                    out[(size_t)n * O_ + o] = acc[m][nf][j] + bv;
                }
            }
        }
    }
    #undef STAGE
    #undef RD_A
    #undef RD_B
    #undef MFMA16
    #undef VMCNT4
    #undef VMCNT2
    #undef VMCNT0
    #undef LGKM0
    #undef BAR
}

// ---------------------------------------------------------------------------
extern "C" void kernel_launch(void* const* d_in, const int* in_sizes, int n_in,
                              void* d_out, int out_size, void* d_ws, size_t ws_size,
                              hipStream_t stream) {
    const float* X      = (const float*)d_in[0];
    const float* ctx    = (const float*)d_in[1];
    const float* W      = (const float*)d_in[2];
    const float* bias   = (const float*)d_in[3];
    const float* protos = (const float*)d_in[4];
    float* out = (float*)d_out;

    char* ws = (char*)d_ws;
    unsigned char* best = (unsigned char*)ws;                         // 8 MiB
    float* psq = (float*)(ws + ((size_t)8 << 20));                    // 32 KiB
    unsigned short* Xb = (unsigned short*)(ws + ((size_t)9 << 20));   // 16 MiB
    unsigned short* Wb = (unsigned short*)(ws + ((size_t)25 << 20));  // 16 MiB
    unsigned* wl_cnt = (unsigned*)(ws + ((size_t)41 << 20));          // 4 B

    // scratch in d_out (fully overwritten by gemm later)
    char* ob = (char*)d_out;
    unsigned short* ph = (unsigned short*)(ob + ((size_t)16 << 20));  // 1 MiB
    unsigned short* pl = (unsigned short*)(ob + ((size_t)17 << 20));  // 1 MiB
    unsigned short* ch = (unsigned short*)(ob + ((size_t)18 << 20));  // 1 MiB
    unsigned short* cl = (unsigned short*)(ob + ((size_t)19 << 20));  // 1 MiB
    unsigned* wl = (unsigned*)(ob + ((size_t)20 << 20));              // 8 MiB (2M entries)

    hipFuncSetAttribute((const void*)gemm_gather_kernel,
                        hipFuncAttributeMaxDynamicSharedMemorySize, 131072);

    hipMemsetAsync(wl_cnt, 0, 4, stream);
    convert_tiled_kernel<0><<<dim3(4096), dim3(256), 0, stream>>>(X, Xb);
    convert_tiled_kernel<1><<<dim3(4096), dim3(256), 0, stream>>>(W, Wb);
    prep_kernel<<<dim3(544), dim3(256), 0, stream>>>(protos, ctx, ph, pl, ch, cl, psq);
    argmin_mfma_kernel<<<dim3(OP_ / 128, N_ / 128), dim3(256), 0, stream>>>(ph, pl, ch, cl, psq, best);
    compact_kernel<<<dim3(1024), dim3(256), 0, stream>>>((const uint4*)best, wl, wl_cnt);
    refine_wl_kernel<<<dim3(1024), dim3(256), 0, stream>>>(ctx, protos, wl, wl_cnt, best);
    gemm_gather_kernel<<<dim3(1024), dim3(512), 131072, stream>>>(Xb, Wb, bias, best, out);
}